// Round 2
// baseline (4417.750 us; speedup 1.0000x reference)
//
#include <hip/hip_runtime.h>

// GINEEncoderBlock — round 4: edge GEMM was at the LDS-bandwidth roofline.
// R3 profile: edge GEMM 551us, VALUBusy 80%, conflicts ~0, HBM 10%.
// Model: 4x16 thread tile reads 80B LDS per 64 FMA = 1.25 B/FMA ->
// 160 B/cyc/CU demand vs 128 B/cyc LDS peak -> VALU duty 128/160 = 80%
// (matches measured 80.0%). Fix: 8x16 thread tile (128-row block tile):
// 96B per 128 FMA = 0.75 B/FMA -> 96 B/cyc < peak -> VALU-bound.
// Node GEMMs stay 4x16 (64-row tiles) for grid occupancy (N=10k only).

#define D 256
#define BN_EPS 1e-5f

// ------------------------------------------------------------- CSR build ----
__global__ __launch_bounds__(256) void hist_kernel(
    const int* __restrict__ dst, int* __restrict__ cnt, int E)
{
    int i = blockIdx.x * 256 + threadIdx.x;
    if (i < E) atomicAdd(&cnt[dst[i]], 1);
}

// single-block inclusive scan -> row_ptr[1..N]; row_ptr[0]=0
__global__ __launch_bounds__(256) void scan_kernel(
    const int* __restrict__ cnt, int* __restrict__ row_ptr, int N)
{
    __shared__ int buf[256];
    __shared__ int carry_s;
    if (threadIdx.x == 0) { carry_s = 0; row_ptr[0] = 0; }
    __syncthreads();
    for (int base = 0; base < N; base += 256) {
        int i = base + threadIdx.x;
        int v = (i < N) ? cnt[i] : 0;
        buf[threadIdx.x] = v;
        __syncthreads();
#pragma unroll
        for (int off = 1; off < 256; off <<= 1) {
            int t = (threadIdx.x >= off) ? buf[threadIdx.x - off] : 0;
            __syncthreads();
            buf[threadIdx.x] += t;
            __syncthreads();
        }
        int inc = buf[threadIdx.x] + carry_s;
        if (i < N) row_ptr[i + 1] = inc;
        __syncthreads();
        if (threadIdx.x == 255) carry_s = inc;
        __syncthreads();
    }
}

__global__ __launch_bounds__(256) void fill_kernel(
    const int* __restrict__ dst, const int* __restrict__ row_ptr,
    int* __restrict__ fillc, int* __restrict__ edge_idx, int E)
{
    int i = blockIdx.x * 256 + threadIdx.x;
    if (i < E) {
        int d = dst[i];
        int pos = atomicAdd(&fillc[d], 1);
        edge_idx[row_ptr[d] + pos] = i;
    }
}

// ---------------------------------------------------------------- gather ----
// one wave per node; lane holds float4 (256 cols); sum relu(x[src]+e) over
// the node's incoming edges (CSR). Plain loads, single coalesced write.
__global__ __launch_bounds__(256) void gather_aggr(
    const float* __restrict__ x, const float* __restrict__ e,
    const int* __restrict__ src, const int* __restrict__ row_ptr,
    const int* __restrict__ edge_idx, float* __restrict__ aggr, int N)
{
    int node = blockIdx.x * 4 + (threadIdx.x >> 6);
    if (node >= N) return;
    int lane = threadIdx.x & 63;
    int beg = row_ptr[node], end = row_ptr[node + 1];
    float4 acc = make_float4(0.f, 0.f, 0.f, 0.f);
    for (int j = beg; j < end; ++j) {
        int ed = edge_idx[j];
        int s = src[ed];
        float4 ev = ((const float4*)(e + (size_t)ed * D))[lane];
        float4 xv = ((const float4*)(x + (size_t)s * D))[lane];
        acc.x += fmaxf(ev.x + xv.x, 0.f);
        acc.y += fmaxf(ev.y + xv.y, 0.f);
        acc.z += fmaxf(ev.z + xv.z, 0.f);
        acc.w += fmaxf(ev.w + xv.w, 0.f);
    }
    ((float4*)(aggr + (size_t)node * D))[lane] = acc;
}

// ------------------------------------------------------------------- GEMM ----
// Each block: (RPT*16) rows x FULL 256 cols (in-place safe: sole reader +
// writer of its rows). 256 thr = 16x16; thread computes RPT rows x 16 cols,
// cols strided: col = jc*64 + tx*4 (Bs reads 256B-contiguous across tx ->
// 2-way bank access = free; epilogue stores 256B contiguous). K-chunk 16.
// RPT=8 for the big edge GEMM (0.75 B LDS per FMA -> below LDS BW roof),
// RPT=4 for node GEMMs (more blocks, N is small).
template<int RPT, bool HAS_AGGR, bool ADD_INIT>
__global__ __launch_bounds__(256) void gemm_rowfull(
    const float* A, const float* __restrict__ aggr,
    const float* __restrict__ W, const float* __restrict__ bias,
    const float* __restrict__ init, float* out, int rows)
{
    constexpr int BROWS = RPT * 16;
    __shared__ float As[16][BROWS + 4];
    __shared__ float Bs[16][260];

    const int tid = threadIdx.x;
    const int m0 = blockIdx.x * BROWS;
    const int tx = tid & 15;
    const int ty = tid >> 4;

    const int bk  = tid >> 4;
    const int bn4 = (tid & 15) << 2;

    float acc[RPT][16];
#pragma unroll
    for (int i = 0; i < RPT; ++i)
#pragma unroll
        for (int j = 0; j < 16; ++j) acc[i][j] = 0.f;

    for (int k0 = 0; k0 < D; k0 += 16) {
        // ---- stage A (transposed): BROWS rows x 16 k-floats ----
#pragma unroll
        for (int it = 0; it < RPT / 4; ++it) {
            int row = (tid >> 2) + it * 64;
            int c4  = (tid & 3) << 2;
            int gr  = m0 + row;
            float4 av = make_float4(0.f, 0.f, 0.f, 0.f);
            if (gr < rows) {
                av = *(const float4*)(A + (size_t)gr * D + k0 + c4);
                if (HAS_AGGR) {
                    float4 g = *(const float4*)(aggr + (size_t)gr * D + k0 + c4);
                    av.x += g.x; av.y += g.y; av.z += g.z; av.w += g.w;
                }
            }
            As[c4 + 0][row] = av.x;
            As[c4 + 1][row] = av.y;
            As[c4 + 2][row] = av.z;
            As[c4 + 3][row] = av.w;
        }
        // ---- stage B: 16 k-rows x 256 cols ----
#pragma unroll
        for (int c = 0; c < 4; ++c)
            *(float4*)&Bs[bk][c * 64 + bn4] =
                *(const float4*)(W + (size_t)(k0 + bk) * D + c * 64 + bn4);
        __syncthreads();
#pragma unroll
        for (int k = 0; k < 16; ++k) {
            float a[RPT];
#pragma unroll
            for (int r4 = 0; r4 < RPT / 4; ++r4) {
                float4 a4 = *(const float4*)&As[k][ty * RPT + r4 * 4];
                a[r4 * 4 + 0] = a4.x;
                a[r4 * 4 + 1] = a4.y;
                a[r4 * 4 + 2] = a4.z;
                a[r4 * 4 + 3] = a4.w;
            }
#pragma unroll
            for (int jc = 0; jc < 4; ++jc) {
                float4 b4 = *(const float4*)&Bs[k][(jc << 6) + (tx << 2)];
#pragma unroll
                for (int i = 0; i < RPT; ++i) {
                    acc[i][jc * 4 + 0] += a[i] * b4.x;
                    acc[i][jc * 4 + 1] += a[i] * b4.y;
                    acc[i][jc * 4 + 2] += a[i] * b4.z;
                    acc[i][jc * 4 + 3] += a[i] * b4.w;
                }
            }
        }
        __syncthreads();
    }

#pragma unroll
    for (int jc = 0; jc < 4; ++jc) {
        int col = (jc << 6) + (tx << 2);
        float4 bias4 = *(const float4*)(bias + col);
#pragma unroll
        for (int i = 0; i < RPT; ++i) {
            int gr = m0 + ty * RPT + i;
            if (gr < rows) {
                float4 o;
                o.x = fmaxf(acc[i][jc * 4 + 0] + bias4.x, 0.f);
                o.y = fmaxf(acc[i][jc * 4 + 1] + bias4.y, 0.f);
                o.z = fmaxf(acc[i][jc * 4 + 2] + bias4.z, 0.f);
                o.w = fmaxf(acc[i][jc * 4 + 3] + bias4.w, 0.f);
                if (ADD_INIT) {
                    float4 iv = *(const float4*)(init + (size_t)gr * D + col);
                    o.x += iv.x; o.y += iv.y; o.z += iv.z; o.w += iv.w;
                }
                *(float4*)(out + (size_t)gr * D + col) = o;
            }
        }
    }
}

// --------------------------------------------------------------------- BN ----
__global__ __launch_bounds__(256) void bn_stats_kernel(
    const float* __restrict__ x, float* __restrict__ stats, int N)
{
    int col = threadIdx.x;
    float s = 0.f, s2 = 0.f;
    for (int r = blockIdx.x; r < N; r += gridDim.x) {
        float v = x[(size_t)r * D + col];
        s += v; s2 += v * v;
    }
    atomicAdd(&stats[col], s);
    atomicAdd(&stats[D + col], s2);
}

__global__ __launch_bounds__(256) void bn_apply_kernel(
    float* __restrict__ x, const float* __restrict__ stats,
    const float* __restrict__ gamma, const float* __restrict__ beta, int N)
{
    int col = threadIdx.x;
    float inv_n = 1.f / (float)N;
    float mean = stats[col] * inv_n;
    float var  = stats[D + col] * inv_n - mean * mean;
    float scale = gamma[col] * rsqrtf(var + BN_EPS);
    float shift = beta[col] - mean * scale;
    for (int r = blockIdx.x; r < N; r += gridDim.x) {
        size_t idx = (size_t)r * D + col;
        x[idx] = x[idx] * scale + shift;
    }
}

// ----------------------------------------------------------------- launch ----
extern "C" void kernel_launch(void* const* d_in, const int* in_sizes, int n_in,
                              void* d_out, int out_size, void* d_ws, size_t ws_size,
                              hipStream_t stream)
{
    const float* node_feat = (const float*)d_in[0];
    float*       e         = (float*)d_in[1];   // in place (harness restores)
    const int*   src       = (const int*)d_in[2];
    const int*   dst       = (const int*)d_in[3];
    const float* W_conv    = (const float*)d_in[4];
    const float* b_conv    = (const float*)d_in[5];
    const float* W_edge    = (const float*)d_in[6];
    const float* b_edge    = (const float*)d_in[7];
    const float* gamma     = (const float*)d_in[8];
    const float* beta      = (const float*)d_in[9];
    float*       out       = (float*)d_out;

    const int N = in_sizes[0] / D;
    const int E = in_sizes[2];
    const int L = in_sizes[5] / D;

    float* x        = (float*)d_ws;                  // N*D f32
    float* aggr     = x + (size_t)N * D;             // N*D f32
    float* stats    = aggr + (size_t)N * D;          // 2*D f32
    int*   cnt      = (int*)(stats + 2 * D);         // N
    int*   row_ptr  = cnt + N;                       // N+1
    int*   fillc    = row_ptr + N + 1;               // N
    int*   edge_idx = fillc + N;                     // E

    int nodeBlocks    = (N + 63) / 64;
    int edgeBlocks    = (E + 127) / 128;
    int gatherBlocks  = (N + 3) / 4;
    int eThreadBlocks = (E + 255) / 256;

    // ---- build CSR once (dst fixed for the whole call) ----
    hipMemsetAsync(cnt, 0, (size_t)N * sizeof(int), stream);
    hipMemsetAsync(fillc, 0, (size_t)N * sizeof(int), stream);
    hist_kernel<<<eThreadBlocks, 256, 0, stream>>>(dst, cnt, E);
    scan_kernel<<<1, 256, 0, stream>>>(cnt, row_ptr, N);
    fill_kernel<<<eThreadBlocks, 256, 0, stream>>>(dst, row_ptr, fillc, edge_idx, E);

    const float* xin = node_feat;
    for (int i = 0; i < L; ++i) {
        gather_aggr<<<gatherBlocks, 256, 0, stream>>>(
            xin, e, src, row_ptr, edge_idx, aggr, N);
        gemm_rowfull<4, true, false><<<nodeBlocks, 256, 0, stream>>>(
            xin, aggr, W_conv + (size_t)i * D * D, b_conv + (size_t)i * D,
            nullptr, x, N);
        hipMemsetAsync(stats, 0, 2 * D * sizeof(float), stream);
        bn_stats_kernel<<<512, 256, 0, stream>>>(x, stats, N);
        bn_apply_kernel<<<1024, 256, 0, stream>>>(
            x, stats, gamma + (size_t)i * D, beta + (size_t)i * D, N);
        gemm_rowfull<8, false, false><<<edgeBlocks, 256, 0, stream>>>(
            e, nullptr, W_edge + (size_t)i * D * D, b_edge + (size_t)i * D,
            nullptr, e, E);
        xin = x;
    }

    // final conv: layer L-1 weights on current (x, e), then + node_feat
    gather_aggr<<<gatherBlocks, 256, 0, stream>>>(
        x, e, src, row_ptr, edge_idx, aggr, N);
    gemm_rowfull<4, true, true><<<nodeBlocks, 256, 0, stream>>>(
        x, aggr, W_conv + (size_t)(L - 1) * D * D, b_conv + (size_t)(L - 1) * D,
        node_feat, out, N);
}

// Round 3
// 2908.152 us; speedup vs baseline: 1.5191x; 1.5191x over previous
//
#include <hip/hip_runtime.h>

// GINEEncoderBlock — round 5: MFMA (bf16 hi/lo split) edge GEMM.
// R3 history: fp32 edge GEMM is boxed in: 4x16 tile = LDS-BW-bound (80%
// VALU, 551us); 8x16 tile = VGPR 136 > 128 -> occupancy halves -> 837us.
// Escape: matrix cores. fp32 has no MFMA on CDNA4 -> split each operand
// x = hi(bf16) + lo(bf16); x*w ~ ah*bh + ah*bl + al*bh (3 MFMAs, fp32 acc,
// residual ~2^-16 relative). W_edge pre-converted once to transposed
// k-contiguous bf16 hi/lo (L2-hot, frags read straight from global);
// e staged via LDS as bf16 hi/lo (read from HBM once, conflict-free
// 64B-row layout). Verified layouts: C/D col=lane&15,row=(lane>>4)*4+reg;
// A/B row|col=lane&15, k=(lane>>4)*8+i.

#define D 256
#define BN_EPS 1e-5f

typedef __attribute__((ext_vector_type(8))) short bf16x8;
typedef __attribute__((ext_vector_type(4))) float f32x4;

__device__ __forceinline__ ushort bf16h(float f) {
    uint u = __float_as_uint(f);
    return (ushort)((u + 0x7FFFu + ((u >> 16) & 1u)) >> 16);
}
__device__ __forceinline__ float bf16f(ushort h) {
    return __uint_as_float(((uint)h) << 16);
}

// ------------------------------------------------------------- CSR build ----
__global__ __launch_bounds__(256) void hist_kernel(
    const int* __restrict__ dst, int* __restrict__ cnt, int E)
{
    int i = blockIdx.x * 256 + threadIdx.x;
    if (i < E) atomicAdd(&cnt[dst[i]], 1);
}

__global__ __launch_bounds__(256) void scan_kernel(
    const int* __restrict__ cnt, int* __restrict__ row_ptr, int N)
{
    __shared__ int buf[256];
    __shared__ int carry_s;
    if (threadIdx.x == 0) { carry_s = 0; row_ptr[0] = 0; }
    __syncthreads();
    for (int base = 0; base < N; base += 256) {
        int i = base + threadIdx.x;
        int v = (i < N) ? cnt[i] : 0;
        buf[threadIdx.x] = v;
        __syncthreads();
#pragma unroll
        for (int off = 1; off < 256; off <<= 1) {
            int t = (threadIdx.x >= off) ? buf[threadIdx.x - off] : 0;
            __syncthreads();
            buf[threadIdx.x] += t;
            __syncthreads();
        }
        int inc = buf[threadIdx.x] + carry_s;
        if (i < N) row_ptr[i + 1] = inc;
        __syncthreads();
        if (threadIdx.x == 255) carry_s = inc;
        __syncthreads();
    }
}

__global__ __launch_bounds__(256) void fill_kernel(
    const int* __restrict__ dst, const int* __restrict__ row_ptr,
    int* __restrict__ fillc, int* __restrict__ edge_idx, int E)
{
    int i = blockIdx.x * 256 + threadIdx.x;
    if (i < E) {
        int d = dst[i];
        int pos = atomicAdd(&fillc[d], 1);
        edge_idx[row_ptr[d] + pos] = i;
    }
}

// ---------------------------------------------------------------- gather ----
__global__ __launch_bounds__(256) void gather_aggr(
    const float* __restrict__ x, const float* __restrict__ e,
    const int* __restrict__ src, const int* __restrict__ row_ptr,
    const int* __restrict__ edge_idx, float* __restrict__ aggr, int N)
{
    int node = blockIdx.x * 4 + (threadIdx.x >> 6);
    if (node >= N) return;
    int lane = threadIdx.x & 63;
    int beg = row_ptr[node], end = row_ptr[node + 1];
    float4 acc = make_float4(0.f, 0.f, 0.f, 0.f);
    for (int j = beg; j < end; ++j) {
        int ed = edge_idx[j];
        int s = src[ed];
        float4 ev = ((const float4*)(e + (size_t)ed * D))[lane];
        float4 xv = ((const float4*)(x + (size_t)s * D))[lane];
        acc.x += fmaxf(ev.x + xv.x, 0.f);
        acc.y += fmaxf(ev.y + xv.y, 0.f);
        acc.z += fmaxf(ev.z + xv.z, 0.f);
        acc.w += fmaxf(ev.w + xv.w, 0.f);
    }
    ((float4*)(aggr + (size_t)node * D))[lane] = acc;
}

// ------------------------------------------- W -> transposed bf16 hi/lo -----
// one block per (layer,k) row; thread = col. WT[layer][col][k], k-contiguous.
__global__ __launch_bounds__(256) void wconv_kernel(
    const float* __restrict__ W, ushort* __restrict__ WTh,
    ushort* __restrict__ WTl)
{
    int bk = blockIdx.x;            // layer*D + k
    int col = threadIdx.x;
    int layer = bk >> 8, k = bk & 255;
    float v = W[(size_t)bk * D + col];
    ushort h = bf16h(v);
    ushort lo = bf16h(v - bf16f(h));
    size_t o = ((size_t)layer * D + col) * D + k;
    WTh[o] = h;
    WTl[o] = lo;
}

// ----------------------------------------------------- MFMA edge GEMM -------
// block = 64 rows x 256 cols (in-place safe), 4 waves, wave tile 64x64.
// A (e rows) staged in LDS as bf16 hi/lo [64][32] per K-chunk (64B rows ->
// staging writes and frag reads each cover contiguous 1KB/wave: conflict-
// free). W frags read directly from global bf16 (L2-hot).
__global__ __launch_bounds__(256) void gemm_edge_mfma(
    const float* __restrict__ A, const ushort* __restrict__ WTh,
    const ushort* __restrict__ WTl, const float* __restrict__ bias,
    float* __restrict__ out, int rows)
{
    __shared__ ushort Ah[64 * 32];
    __shared__ ushort Al[64 * 32];

    const int tid  = threadIdx.x;
    const int lane = tid & 63;
    const int wave = tid >> 6;
    const int m0   = blockIdx.x * 64;
    const int l15  = lane & 15;
    const int l4   = lane >> 4;
    const int wcol = wave * 64;

    f32x4 acc[4][4];
#pragma unroll
    for (int m = 0; m < 4; ++m)
#pragma unroll
        for (int n = 0; n < 4; ++n) acc[m][n] = (f32x4){0.f, 0.f, 0.f, 0.f};

    const int srow = tid >> 3;   // 0..31
    const int su   = tid & 7;    // 16B unit within a 128B k-row chunk

    for (int k0 = 0; k0 < D; k0 += 32) {
        // ---- stage A chunk: 64 rows x 32 k, fp32 -> bf16 hi/lo ----
#pragma unroll
        for (int i = 0; i < 2; ++i) {
            int row = srow + i * 32;
            int gr  = m0 + row;
            float4 v = make_float4(0.f, 0.f, 0.f, 0.f);
            if (gr < rows)
                v = *(const float4*)(A + (size_t)gr * D + k0 + su * 4);
            ushort4 h, lo;
            h.x = bf16h(v.x); lo.x = bf16h(v.x - bf16f(h.x));
            h.y = bf16h(v.y); lo.y = bf16h(v.y - bf16f(h.y));
            h.z = bf16h(v.z); lo.z = bf16h(v.z - bf16f(h.z));
            h.w = bf16h(v.w); lo.w = bf16h(v.w - bf16f(h.w));
            *(ushort4*)&Ah[row * 32 + su * 4] = h;
            *(ushort4*)&Al[row * 32 + su * 4] = lo;
        }
        __syncthreads();

        // ---- W fragments straight from global (bf16, k-contiguous) ----
        bf16x8 bh[4], bl[4];
#pragma unroll
        for (int n = 0; n < 4; ++n) {
            size_t co = (size_t)(wcol + n * 16 + l15) * D + k0 + l4 * 8;
            bh[n] = *(const bf16x8*)(WTh + co);
            bl[n] = *(const bf16x8*)(WTl + co);
        }

#pragma unroll
        for (int m = 0; m < 4; ++m) {
            int ab = (m * 16 + l15) * 32 + l4 * 8;
            bf16x8 ah = *(const bf16x8*)&Ah[ab];
            bf16x8 al = *(const bf16x8*)&Al[ab];
#pragma unroll
            for (int n = 0; n < 4; ++n) {
                acc[m][n] = __builtin_amdgcn_mfma_f32_16x16x32_bf16(
                    ah, bh[n], acc[m][n], 0, 0, 0);
                acc[m][n] = __builtin_amdgcn_mfma_f32_16x16x32_bf16(
                    ah, bl[n], acc[m][n], 0, 0, 0);
                acc[m][n] = __builtin_amdgcn_mfma_f32_16x16x32_bf16(
                    al, bh[n], acc[m][n], 0, 0, 0);
            }
        }
        __syncthreads();
    }

    // ---- epilogue: relu(acc + bias), scattered dword stores ----
#pragma unroll
    for (int n = 0; n < 4; ++n) {
        int col = wcol + n * 16 + l15;
        float bv = bias[col];
#pragma unroll
        for (int m = 0; m < 4; ++m) {
            int r0 = m0 + m * 16 + l4 * 4;
#pragma unroll
            for (int r = 0; r < 4; ++r) {
                if (r0 + r < rows)
                    out[(size_t)(r0 + r) * D + col] =
                        fmaxf(acc[m][n][r] + bv, 0.f);
            }
        }
    }
}

// ------------------------------------------------------------------- GEMM ----
// fp32 row-full GEMM for node convs (N=10k only). 64 rows x 256 cols/block,
// thread = 4 rows x 16 cols (cols strided jc*64+tx*4: conflict-free).
template<bool HAS_AGGR, bool ADD_INIT>
__global__ __launch_bounds__(256) void gemm_rowfull(
    const float* A, const float* __restrict__ aggr,
    const float* __restrict__ W, const float* __restrict__ bias,
    const float* __restrict__ init, float* out, int rows)
{
    __shared__ float As[16][68];
    __shared__ float Bs[16][260];

    const int tid = threadIdx.x;
    const int m0 = blockIdx.x * 64;
    const int tx = tid & 15;
    const int ty = tid >> 4;

    const int arow = tid >> 2;
    const int ak4  = (tid & 3) << 2;
    const int bk   = tid >> 4;
    const int bn4  = (tid & 15) << 2;

    float acc[4][16];
#pragma unroll
    for (int i = 0; i < 4; ++i)
#pragma unroll
        for (int j = 0; j < 16; ++j) acc[i][j] = 0.f;

    for (int k0 = 0; k0 < D; k0 += 16) {
        float4 av = make_float4(0.f, 0.f, 0.f, 0.f);
        int gr = m0 + arow;
        if (gr < rows) {
            av = *(const float4*)(A + (size_t)gr * D + k0 + ak4);
            if (HAS_AGGR) {
                float4 g = *(const float4*)(aggr + (size_t)gr * D + k0 + ak4);
                av.x += g.x; av.y += g.y; av.z += g.z; av.w += g.w;
            }
        }
        As[ak4 + 0][arow] = av.x;
        As[ak4 + 1][arow] = av.y;
        As[ak4 + 2][arow] = av.z;
        As[ak4 + 3][arow] = av.w;
#pragma unroll
        for (int c = 0; c < 4; ++c)
            *(float4*)&Bs[bk][c * 64 + bn4] =
                *(const float4*)(W + (size_t)(k0 + bk) * D + c * 64 + bn4);
        __syncthreads();
#pragma unroll
        for (int k = 0; k < 16; ++k) {
            float4 a4 = *(const float4*)&As[k][ty << 2];
            float a[4] = {a4.x, a4.y, a4.z, a4.w};
#pragma unroll
            for (int jc = 0; jc < 4; ++jc) {
                float4 b4 = *(const float4*)&Bs[k][(jc << 6) + (tx << 2)];
#pragma unroll
                for (int i = 0; i < 4; ++i) {
                    acc[i][jc * 4 + 0] += a[i] * b4.x;
                    acc[i][jc * 4 + 1] += a[i] * b4.y;
                    acc[i][jc * 4 + 2] += a[i] * b4.z;
                    acc[i][jc * 4 + 3] += a[i] * b4.w;
                }
            }
        }
        __syncthreads();
    }

#pragma unroll
    for (int jc = 0; jc < 4; ++jc) {
        int col = (jc << 6) + (tx << 2);
        float4 bias4 = *(const float4*)(bias + col);
#pragma unroll
        for (int i = 0; i < 4; ++i) {
            int gr = m0 + (ty << 2) + i;
            if (gr < rows) {
                float4 o;
                o.x = fmaxf(acc[i][jc * 4 + 0] + bias4.x, 0.f);
                o.y = fmaxf(acc[i][jc * 4 + 1] + bias4.y, 0.f);
                o.z = fmaxf(acc[i][jc * 4 + 2] + bias4.z, 0.f);
                o.w = fmaxf(acc[i][jc * 4 + 3] + bias4.w, 0.f);
                if (ADD_INIT) {
                    float4 iv = *(const float4*)(init + (size_t)gr * D + col);
                    o.x += iv.x; o.y += iv.y; o.z += iv.z; o.w += iv.w;
                }
                *(float4*)(out + (size_t)gr * D + col) = o;
            }
        }
    }
}

// --------------------------------------------------------------------- BN ----
__global__ __launch_bounds__(256) void bn_stats_kernel(
    const float* __restrict__ x, float* __restrict__ stats, int N)
{
    int col = threadIdx.x;
    float s = 0.f, s2 = 0.f;
    for (int r = blockIdx.x; r < N; r += gridDim.x) {
        float v = x[(size_t)r * D + col];
        s += v; s2 += v * v;
    }
    atomicAdd(&stats[col], s);
    atomicAdd(&stats[D + col], s2);
}

__global__ __launch_bounds__(256) void bn_apply_kernel(
    float* __restrict__ x, const float* __restrict__ stats,
    const float* __restrict__ gamma, const float* __restrict__ beta, int N)
{
    int col = threadIdx.x;
    float inv_n = 1.f / (float)N;
    float mean = stats[col] * inv_n;
    float var  = stats[D + col] * inv_n - mean * mean;
    float scale = gamma[col] * rsqrtf(var + BN_EPS);
    float shift = beta[col] - mean * scale;
    for (int r = blockIdx.x; r < N; r += gridDim.x) {
        size_t idx = (size_t)r * D + col;
        x[idx] = x[idx] * scale + shift;
    }
}

// ----------------------------------------------------------------- launch ----
extern "C" void kernel_launch(void* const* d_in, const int* in_sizes, int n_in,
                              void* d_out, int out_size, void* d_ws, size_t ws_size,
                              hipStream_t stream)
{
    const float* node_feat = (const float*)d_in[0];
    float*       e         = (float*)d_in[1];   // in place (harness restores)
    const int*   src       = (const int*)d_in[2];
    const int*   dst       = (const int*)d_in[3];
    const float* W_conv    = (const float*)d_in[4];
    const float* b_conv    = (const float*)d_in[5];
    const float* W_edge    = (const float*)d_in[6];
    const float* b_edge    = (const float*)d_in[7];
    const float* gamma     = (const float*)d_in[8];
    const float* beta      = (const float*)d_in[9];
    float*       out       = (float*)d_out;

    const int N = in_sizes[0] / D;
    const int E = in_sizes[2];
    const int L = in_sizes[5] / D;

    float* x        = (float*)d_ws;                  // N*D f32
    float* aggr     = x + (size_t)N * D;             // N*D f32
    float* stats    = aggr + (size_t)N * D;          // 2*D f32
    int*   cnt      = (int*)(stats + 2 * D);         // N
    int*   row_ptr  = cnt + N;                       // N+1
    int*   fillc    = row_ptr + N + 1;               // N
    int*   edge_idx = fillc + N;                     // E
    ushort* WTh     = (ushort*)(edge_idx + E);       // L*D*D bf16 hi
    ushort* WTl     = WTh + (size_t)L * D * D;       // L*D*D bf16 lo

    int nodeBlocks    = (N + 63) / 64;
    int edgeBlocks    = (E + 63) / 64;
    int gatherBlocks  = (N + 3) / 4;
    int eThreadBlocks = (E + 255) / 256;

    // ---- one-time: CSR over dst + W_edge -> transposed bf16 hi/lo ----
    hipMemsetAsync(cnt, 0, (size_t)N * sizeof(int), stream);
    hipMemsetAsync(fillc, 0, (size_t)N * sizeof(int), stream);
    hist_kernel<<<eThreadBlocks, 256, 0, stream>>>(dst, cnt, E);
    scan_kernel<<<1, 256, 0, stream>>>(cnt, row_ptr, N);
    fill_kernel<<<eThreadBlocks, 256, 0, stream>>>(dst, row_ptr, fillc, edge_idx, E);
    wconv_kernel<<<L * D, 256, 0, stream>>>(W_edge, WTh, WTl);

    const float* xin = node_feat;
    for (int i = 0; i < L; ++i) {
        gather_aggr<<<gatherBlocks, 256, 0, stream>>>(
            xin, e, src, row_ptr, edge_idx, aggr, N);
        gemm_rowfull<true, false><<<nodeBlocks, 256, 0, stream>>>(
            xin, aggr, W_conv + (size_t)i * D * D, b_conv + (size_t)i * D,
            nullptr, x, N);
        hipMemsetAsync(stats, 0, 2 * D * sizeof(float), stream);
        bn_stats_kernel<<<512, 256, 0, stream>>>(x, stats, N);
        bn_apply_kernel<<<1024, 256, 0, stream>>>(
            x, stats, gamma + (size_t)i * D, beta + (size_t)i * D, N);
        gemm_edge_mfma<<<edgeBlocks, 256, 0, stream>>>(
            e, WTh + (size_t)i * D * D, WTl + (size_t)i * D * D,
            b_edge + (size_t)i * D, e, E);
        xin = x;
    }

    // final conv: layer L-1 weights on current (x, e), then + node_feat
    gather_aggr<<<gatherBlocks, 256, 0, stream>>>(
        x, e, src, row_ptr, edge_idx, aggr, N);
    gemm_rowfull<true, true><<<nodeBlocks, 256, 0, stream>>>(
        x, aggr, W_conv + (size_t)(L - 1) * D * D, b_conv + (size_t)(L - 1) * D,
        node_feat, out, N);
}

// Round 4
// 2366.268 us; speedup vs baseline: 1.8670x; 1.2290x over previous
//
#include <hip/hip_runtime.h>

// GINEEncoderBlock — round 6: pipeline the MFMA edge GEMM (no-barrier form).
// R4 profile: edge GEMM 402us with MfmaUtil 12%, VALU 11%, HBM 18% ->
// latency-bound serialization (stage->barrier->load->wait->MFMA->barrier,
// no prefetch, 2 blk/CU). Fix: (1) A fragments loaded fp32 straight from
// global per wave (16 rows x 128B lines, L1-shared across waves) and
// converted in regs -> zero barriers/LDS in K-loop; (2) W re-laid-out
// K-chunk-major [kc][col][32k] -> 1KB contiguous frag reads; (3) one-step
// prefetch of A+W regs under the 48 MFMAs; (4) epilogue LDS transpose ->
// 256B-contiguous float4 stores (was 64B segments, 100MB write-allocate
// amplification). hi/lo 3-MFMA split unchanged (verified numerics).

#define D 256
#define BN_EPS 1e-5f

typedef __attribute__((ext_vector_type(8))) short bf16x8;
typedef __attribute__((ext_vector_type(4))) float f32x4;

__device__ __forceinline__ ushort bf16h(float f) {
    uint u = __float_as_uint(f);
    return (ushort)((u + 0x7FFFu + ((u >> 16) & 1u)) >> 16);
}
__device__ __forceinline__ float bf16f(ushort h) {
    return __uint_as_float(((uint)h) << 16);
}

__device__ __forceinline__ void cvt8(const float4& x0, const float4& x1,
                                     bf16x8& h, bf16x8& l) {
    float f[8] = {x0.x, x0.y, x0.z, x0.w, x1.x, x1.y, x1.z, x1.w};
#pragma unroll
    for (int i = 0; i < 8; ++i) {
        ushort hh = bf16h(f[i]);
        h[i] = (short)hh;
        l[i] = (short)bf16h(f[i] - bf16f(hh));
    }
}

// ------------------------------------------------------------- CSR build ----
__global__ __launch_bounds__(256) void hist_kernel(
    const int* __restrict__ dst, int* __restrict__ cnt, int E)
{
    int i = blockIdx.x * 256 + threadIdx.x;
    if (i < E) atomicAdd(&cnt[dst[i]], 1);
}

__global__ __launch_bounds__(256) void scan_kernel(
    const int* __restrict__ cnt, int* __restrict__ row_ptr, int N)
{
    __shared__ int buf[256];
    __shared__ int carry_s;
    if (threadIdx.x == 0) { carry_s = 0; row_ptr[0] = 0; }
    __syncthreads();
    for (int base = 0; base < N; base += 256) {
        int i = base + threadIdx.x;
        int v = (i < N) ? cnt[i] : 0;
        buf[threadIdx.x] = v;
        __syncthreads();
#pragma unroll
        for (int off = 1; off < 256; off <<= 1) {
            int t = (threadIdx.x >= off) ? buf[threadIdx.x - off] : 0;
            __syncthreads();
            buf[threadIdx.x] += t;
            __syncthreads();
        }
        int inc = buf[threadIdx.x] + carry_s;
        if (i < N) row_ptr[i + 1] = inc;
        __syncthreads();
        if (threadIdx.x == 255) carry_s = inc;
        __syncthreads();
    }
}

__global__ __launch_bounds__(256) void fill_kernel(
    const int* __restrict__ dst, const int* __restrict__ row_ptr,
    int* __restrict__ fillc, int* __restrict__ edge_idx, int E)
{
    int i = blockIdx.x * 256 + threadIdx.x;
    if (i < E) {
        int d = dst[i];
        int pos = atomicAdd(&fillc[d], 1);
        edge_idx[row_ptr[d] + pos] = i;
    }
}

// ---------------------------------------------------------------- gather ----
__global__ __launch_bounds__(256) void gather_aggr(
    const float* __restrict__ x, const float* __restrict__ e,
    const int* __restrict__ src, const int* __restrict__ row_ptr,
    const int* __restrict__ edge_idx, float* __restrict__ aggr, int N)
{
    int node = blockIdx.x * 4 + (threadIdx.x >> 6);
    if (node >= N) return;
    int lane = threadIdx.x & 63;
    int beg = row_ptr[node], end = row_ptr[node + 1];
    float4 acc = make_float4(0.f, 0.f, 0.f, 0.f);
    for (int j = beg; j < end; ++j) {
        int ed = edge_idx[j];
        int s = src[ed];
        float4 ev = ((const float4*)(e + (size_t)ed * D))[lane];
        float4 xv = ((const float4*)(x + (size_t)s * D))[lane];
        acc.x += fmaxf(ev.x + xv.x, 0.f);
        acc.y += fmaxf(ev.y + xv.y, 0.f);
        acc.z += fmaxf(ev.z + xv.z, 0.f);
        acc.w += fmaxf(ev.w + xv.w, 0.f);
    }
    ((float4*)(aggr + (size_t)node * D))[lane] = acc;
}

// ------------------------------------------- W -> K-chunk-major bf16 hi/lo --
// WT[layer][kc][col][kw]: kc = k/32, kw = k%32, k-contiguous inner 32.
// Frag read for (col, kc, l4) = 16B at ((kc*256+col)*32 + l4*8): the 16
// consecutive cols of a fragment span 1KB contiguous.
__global__ __launch_bounds__(256) void wconv_kernel(
    const float* __restrict__ W, ushort* __restrict__ WTh,
    ushort* __restrict__ WTl)
{
    int bk = blockIdx.x;            // layer*D + k
    int col = threadIdx.x;
    int layer = bk >> 8, k = bk & 255;
    float v = W[(size_t)bk * D + col];
    ushort h = bf16h(v);
    ushort lo = bf16h(v - bf16f(h));
    size_t o = (((size_t)layer * 8 + (k >> 5)) * 256 + col) * 32 + (k & 31);
    WTh[o] = h;
    WTl[o] = lo;
}

// ----------------------------------------------------- MFMA edge GEMM -------
// block = 64 rows x 256 cols (in-place safe: sole reader+writer of its rows,
// all reads precede stores in wave program order). 4 waves, wave = 64x64
// via 4x4 16x16x32 fragments. NO barriers / NO LDS in the K-loop: A frags
// loaded fp32 from global (coalesced 128B row segments, L1-shared across
// the 4 waves) and converted in-reg; W frags 1KB-contiguous bf16 (L2-hot).
// One-K-step prefetch of both keeps loads in flight under the 48 MFMAs.
__global__ __launch_bounds__(256) void gemm_edge_mfma(
    const float* __restrict__ A, const ushort* __restrict__ WTh,
    const ushort* __restrict__ WTl, const float* __restrict__ bias,
    float* __restrict__ out, int rows)
{
    __shared__ float Tr[4][32][68];   // epilogue transpose, per-wave region

    const int tid  = threadIdx.x;
    const int lane = tid & 63;
    const int wave = tid >> 6;
    const int m0   = blockIdx.x * 64;
    const int l15  = lane & 15;
    const int l4   = lane >> 4;
    const int wcol = wave * 64;

    f32x4 acc[4][4];
#pragma unroll
    for (int m = 0; m < 4; ++m)
#pragma unroll
        for (int n = 0; n < 4; ++n) acc[m][n] = (f32x4){0.f, 0.f, 0.f, 0.f};

    float4 pa[4][2];
    bf16x8 ah[4], al[4], bh[4], bl[4], bhn[4], bln[4];

    // ---- prologue: load kc=0 ----
#pragma unroll
    for (int m = 0; m < 4; ++m) {
        int r = m0 + m * 16 + l15;
        if (r < rows) {
            const float* p = A + (size_t)r * D + l4 * 8;
            pa[m][0] = *(const float4*)p;
            pa[m][1] = *(const float4*)(p + 4);
        } else {
            pa[m][0] = make_float4(0.f, 0.f, 0.f, 0.f);
            pa[m][1] = make_float4(0.f, 0.f, 0.f, 0.f);
        }
    }
#pragma unroll
    for (int n = 0; n < 4; ++n) {
        size_t o = ((size_t)(wcol + n * 16 + l15)) * 32 + l4 * 8;
        bh[n] = *(const bf16x8*)(WTh + o);
        bl[n] = *(const bf16x8*)(WTl + o);
    }
#pragma unroll
    for (int m = 0; m < 4; ++m) cvt8(pa[m][0], pa[m][1], ah[m], al[m]);

    // ---- K loop: 8 chunks of 32, fully unrolled, 1-step prefetch ----
#pragma unroll
    for (int kc = 0; kc < 8; ++kc) {
        if (kc < 7) {
            int k0 = (kc + 1) * 32;
#pragma unroll
            for (int m = 0; m < 4; ++m) {
                int r = m0 + m * 16 + l15;
                if (r < rows) {          // invalid lanes keep prologue zeros
                    const float* p = A + (size_t)r * D + k0 + l4 * 8;
                    pa[m][0] = *(const float4*)p;
                    pa[m][1] = *(const float4*)(p + 4);
                }
            }
#pragma unroll
            for (int n = 0; n < 4; ++n) {
                size_t o = ((size_t)(kc + 1) * 256 + wcol + n * 16 + l15) * 32
                         + l4 * 8;
                bhn[n] = *(const bf16x8*)(WTh + o);
                bln[n] = *(const bf16x8*)(WTl + o);
            }
        }
#pragma unroll
        for (int m = 0; m < 4; ++m)
#pragma unroll
            for (int n = 0; n < 4; ++n) {
                acc[m][n] = __builtin_amdgcn_mfma_f32_16x16x32_bf16(
                    ah[m], bh[n], acc[m][n], 0, 0, 0);
                acc[m][n] = __builtin_amdgcn_mfma_f32_16x16x32_bf16(
                    ah[m], bl[n], acc[m][n], 0, 0, 0);
                acc[m][n] = __builtin_amdgcn_mfma_f32_16x16x32_bf16(
                    al[m], bh[n], acc[m][n], 0, 0, 0);
            }
        if (kc < 7) {
#pragma unroll
            for (int m = 0; m < 4; ++m) cvt8(pa[m][0], pa[m][1], ah[m], al[m]);
#pragma unroll
            for (int n = 0; n < 4; ++n) { bh[n] = bhn[n]; bl[n] = bln[n]; }
        }
    }

    // ---- epilogue: bias+relu, LDS transpose, 256B-contiguous stores ----
#pragma unroll
    for (int h = 0; h < 2; ++h) {
        __syncthreads();
#pragma unroll
        for (int mm = 0; mm < 2; ++mm) {
            int m = h * 2 + mm;
#pragma unroll
            for (int n = 0; n < 4; ++n) {
                float bv = bias[wcol + n * 16 + l15];
#pragma unroll
                for (int r = 0; r < 4; ++r)
                    Tr[wave][mm * 16 + l4 * 4 + r][n * 16 + l15] =
                        fmaxf(acc[m][n][r] + bv, 0.f);
            }
        }
        __syncthreads();
#pragma unroll
        for (int p = 0; p < 8; ++p) {
            int row  = p * 4 + l4;
            int grow = m0 + h * 32 + row;
            if (grow < rows) {
                float4 v = *(const float4*)&Tr[wave][row][l15 * 4];
                *(float4*)(out + (size_t)grow * D + wcol + l15 * 4) = v;
            }
        }
    }
}

// ------------------------------------------------------------------- GEMM ----
// fp32 row-full GEMM for node convs (N=10k only). 64 rows x 256 cols/block,
// thread = 4 rows x 16 cols (cols strided jc*64+tx*4: conflict-free).
template<bool HAS_AGGR, bool ADD_INIT>
__global__ __launch_bounds__(256) void gemm_rowfull(
    const float* A, const float* __restrict__ aggr,
    const float* __restrict__ W, const float* __restrict__ bias,
    const float* __restrict__ init, float* out, int rows)
{
    __shared__ float As[16][68];
    __shared__ float Bs[16][260];

    const int tid = threadIdx.x;
    const int m0 = blockIdx.x * 64;
    const int tx = tid & 15;
    const int ty = tid >> 4;

    const int arow = tid >> 2;
    const int ak4  = (tid & 3) << 2;
    const int bk   = tid >> 4;
    const int bn4  = (tid & 15) << 2;

    float acc[4][16];
#pragma unroll
    for (int i = 0; i < 4; ++i)
#pragma unroll
        for (int j = 0; j < 16; ++j) acc[i][j] = 0.f;

    for (int k0 = 0; k0 < D; k0 += 16) {
        float4 av = make_float4(0.f, 0.f, 0.f, 0.f);
        int gr = m0 + arow;
        if (gr < rows) {
            av = *(const float4*)(A + (size_t)gr * D + k0 + ak4);
            if (HAS_AGGR) {
                float4 g = *(const float4*)(aggr + (size_t)gr * D + k0 + ak4);
                av.x += g.x; av.y += g.y; av.z += g.z; av.w += g.w;
            }
        }
        As[ak4 + 0][arow] = av.x;
        As[ak4 + 1][arow] = av.y;
        As[ak4 + 2][arow] = av.z;
        As[ak4 + 3][arow] = av.w;
#pragma unroll
        for (int c = 0; c < 4; ++c)
            *(float4*)&Bs[bk][c * 64 + bn4] =
                *(const float4*)(W + (size_t)(k0 + bk) * D + c * 64 + bn4);
        __syncthreads();
#pragma unroll
        for (int k = 0; k < 16; ++k) {
            float4 a4 = *(const float4*)&As[k][ty << 2];
            float a[4] = {a4.x, a4.y, a4.z, a4.w};
#pragma unroll
            for (int jc = 0; jc < 4; ++jc) {
                float4 b4 = *(const float4*)&Bs[k][(jc << 6) + (tx << 2)];
#pragma unroll
                for (int i = 0; i < 4; ++i) {
                    acc[i][jc * 4 + 0] += a[i] * b4.x;
                    acc[i][jc * 4 + 1] += a[i] * b4.y;
                    acc[i][jc * 4 + 2] += a[i] * b4.z;
                    acc[i][jc * 4 + 3] += a[i] * b4.w;
                }
            }
        }
        __syncthreads();
    }

#pragma unroll
    for (int jc = 0; jc < 4; ++jc) {
        int col = (jc << 6) + (tx << 2);
        float4 bias4 = *(const float4*)(bias + col);
#pragma unroll
        for (int i = 0; i < 4; ++i) {
            int gr = m0 + (ty << 2) + i;
            if (gr < rows) {
                float4 o;
                o.x = fmaxf(acc[i][jc * 4 + 0] + bias4.x, 0.f);
                o.y = fmaxf(acc[i][jc * 4 + 1] + bias4.y, 0.f);
                o.z = fmaxf(acc[i][jc * 4 + 2] + bias4.z, 0.f);
                o.w = fmaxf(acc[i][jc * 4 + 3] + bias4.w, 0.f);
                if (ADD_INIT) {
                    float4 iv = *(const float4*)(init + (size_t)gr * D + col);
                    o.x += iv.x; o.y += iv.y; o.z += iv.z; o.w += iv.w;
                }
                *(float4*)(out + (size_t)gr * D + col) = o;
            }
        }
    }
}

// --------------------------------------------------------------------- BN ----
__global__ __launch_bounds__(256) void bn_stats_kernel(
    const float* __restrict__ x, float* __restrict__ stats, int N)
{
    int col = threadIdx.x;
    float s = 0.f, s2 = 0.f;
    for (int r = blockIdx.x; r < N; r += gridDim.x) {
        float v = x[(size_t)r * D + col];
        s += v; s2 += v * v;
    }
    atomicAdd(&stats[col], s);
    atomicAdd(&stats[D + col], s2);
}

__global__ __launch_bounds__(256) void bn_apply_kernel(
    float* __restrict__ x, const float* __restrict__ stats,
    const float* __restrict__ gamma, const float* __restrict__ beta, int N)
{
    int col = threadIdx.x;
    float inv_n = 1.f / (float)N;
    float mean = stats[col] * inv_n;
    float var  = stats[D + col] * inv_n - mean * mean;
    float scale = gamma[col] * rsqrtf(var + BN_EPS);
    float shift = beta[col] - mean * scale;
    for (int r = blockIdx.x; r < N; r += gridDim.x) {
        size_t idx = (size_t)r * D + col;
        x[idx] = x[idx] * scale + shift;
    }
}

// ----------------------------------------------------------------- launch ----
extern "C" void kernel_launch(void* const* d_in, const int* in_sizes, int n_in,
                              void* d_out, int out_size, void* d_ws, size_t ws_size,
                              hipStream_t stream)
{
    const float* node_feat = (const float*)d_in[0];
    float*       e         = (float*)d_in[1];   // in place (harness restores)
    const int*   src       = (const int*)d_in[2];
    const int*   dst       = (const int*)d_in[3];
    const float* W_conv    = (const float*)d_in[4];
    const float* b_conv    = (const float*)d_in[5];
    const float* W_edge    = (const float*)d_in[6];
    const float* b_edge    = (const float*)d_in[7];
    const float* gamma     = (const float*)d_in[8];
    const float* beta      = (const float*)d_in[9];
    float*       out       = (float*)d_out;

    const int N = in_sizes[0] / D;
    const int E = in_sizes[2];
    const int L = in_sizes[5] / D;

    float* x        = (float*)d_ws;                  // N*D f32
    float* aggr     = x + (size_t)N * D;             // N*D f32
    float* stats    = aggr + (size_t)N * D;          // 2*D f32
    int*   cnt      = (int*)(stats + 2 * D);         // N
    int*   row_ptr  = cnt + N;                       // N+1
    int*   fillc    = row_ptr + N + 1;               // N
    int*   edge_idx = fillc + N;                     // E
    ushort* WTh     = (ushort*)(edge_idx + E);       // L*D*D bf16 hi
    ushort* WTl     = WTh + (size_t)L * D * D;       // L*D*D bf16 lo

    int nodeBlocks    = (N + 63) / 64;
    int edgeBlocks    = (E + 63) / 64;
    int gatherBlocks  = (N + 3) / 4;
    int eThreadBlocks = (E + 255) / 256;

    // ---- one-time: CSR over dst + W_edge -> K-chunk-major bf16 hi/lo ----
    hipMemsetAsync(cnt, 0, (size_t)N * sizeof(int), stream);
    hipMemsetAsync(fillc, 0, (size_t)N * sizeof(int), stream);
    hist_kernel<<<eThreadBlocks, 256, 0, stream>>>(dst, cnt, E);
    scan_kernel<<<1, 256, 0, stream>>>(cnt, row_ptr, N);
    fill_kernel<<<eThreadBlocks, 256, 0, stream>>>(dst, row_ptr, fillc, edge_idx, E);
    wconv_kernel<<<L * D, 256, 0, stream>>>(W_edge, WTh, WTl);

    const float* xin = node_feat;
    for (int i = 0; i < L; ++i) {
        gather_aggr<<<gatherBlocks, 256, 0, stream>>>(
            xin, e, src, row_ptr, edge_idx, aggr, N);
        gemm_rowfull<true, false><<<nodeBlocks, 256, 0, stream>>>(
            xin, aggr, W_conv + (size_t)i * D * D, b_conv + (size_t)i * D,
            nullptr, x, N);
        hipMemsetAsync(stats, 0, 2 * D * sizeof(float), stream);
        bn_stats_kernel<<<512, 256, 0, stream>>>(x, stats, N);
        bn_apply_kernel<<<1024, 256, 0, stream>>>(
            x, stats, gamma + (size_t)i * D, beta + (size_t)i * D, N);
        gemm_edge_mfma<<<edgeBlocks, 256, 0, stream>>>(
            e, WTh + (size_t)i * D * D, WTl + (size_t)i * D * D,
            b_edge + (size_t)i * D, e, E);
        xin = x;
    }

    // final conv: layer L-1 weights on current (x, e), then + node_feat
    gather_aggr<<<gatherBlocks, 256, 0, stream>>>(
        x, e, src, row_ptr, edge_idx, aggr, N);
    gemm_rowfull<true, true><<<nodeBlocks, 256, 0, stream>>>(
        x, aggr, W_conv + (size_t)(L - 1) * D * D, b_conv + (size_t)(L - 1) * D,
        node_feat, out, N);
}

// Round 5
// 2034.628 us; speedup vs baseline: 2.1713x; 1.1630x over previous
//
#include <hip/hip_runtime.h>

// GINEEncoderBlock — round 7: LDS-staged, single-barrier pipelined MFMA
// edge GEMM. R5 profile: 305us, MfmaUtil 16, VALU 28, HBM 19 -> >50% stall.
// Root causes: (1) all 4 waves converted the SAME 64 A-rows (4x redundant
// VALU, 205k cyc/CU); (2) VGPR 120 + 64 AGPR = 184 unified -> 2 waves/SIMD,
// nothing hides the per-wave stalls. Fix: convert A once per block into
// double-buffered LDS (truncation split: 4 VALU/elem, pair still ~2^-16);
// one barrier per K-step; A-loads for k+1 issued before the 48 MFMAs of k
// (latency hidden, no load crosses a barrier). LDS rows padded to 80B ->
// all frag reads/writes 2-way bank access (free). HBM floor 72us/GEMM.

#define D 256
#define BN_EPS 1e-5f

typedef __attribute__((ext_vector_type(8))) short bf16x8;
typedef __attribute__((ext_vector_type(8))) ushort u16x8;
typedef __attribute__((ext_vector_type(4))) float f32x4;

__device__ __forceinline__ ushort bf16h(float f) {
    uint u = __float_as_uint(f);
    return (ushort)((u + 0x7FFFu + ((u >> 16) & 1u)) >> 16);
}
__device__ __forceinline__ float bf16f(ushort h) {
    return __uint_as_float(((uint)h) << 16);
}

// truncation split: h = top16(f), l = top16(f - h). 4 VALU ops/elem;
// h+l represents f to ~2^-16 relative (truncation shifts weight into l).
__device__ __forceinline__ void cvt_write8(const float4& x0, const float4& x1,
                                           ushort* dh, ushort* dl) {
    float f[8] = {x0.x, x0.y, x0.z, x0.w, x1.x, x1.y, x1.z, x1.w};
    u16x8 hv, lv;
#pragma unroll
    for (int j = 0; j < 8; ++j) {
        uint u = __float_as_uint(f[j]);
        hv[j] = (ushort)(u >> 16);
        float r = f[j] - __uint_as_float(u & 0xFFFF0000u);
        lv[j] = (ushort)(__float_as_uint(r) >> 16);
    }
    *(u16x8*)dh = hv;
    *(u16x8*)dl = lv;
}

// ------------------------------------------------------------- CSR build ----
__global__ __launch_bounds__(256) void hist_kernel(
    const int* __restrict__ dst, int* __restrict__ cnt, int E)
{
    int i = blockIdx.x * 256 + threadIdx.x;
    if (i < E) atomicAdd(&cnt[dst[i]], 1);
}

__global__ __launch_bounds__(256) void scan_kernel(
    const int* __restrict__ cnt, int* __restrict__ row_ptr, int N)
{
    __shared__ int buf[256];
    __shared__ int carry_s;
    if (threadIdx.x == 0) { carry_s = 0; row_ptr[0] = 0; }
    __syncthreads();
    for (int base = 0; base < N; base += 256) {
        int i = base + threadIdx.x;
        int v = (i < N) ? cnt[i] : 0;
        buf[threadIdx.x] = v;
        __syncthreads();
#pragma unroll
        for (int off = 1; off < 256; off <<= 1) {
            int t = (threadIdx.x >= off) ? buf[threadIdx.x - off] : 0;
            __syncthreads();
            buf[threadIdx.x] += t;
            __syncthreads();
        }
        int inc = buf[threadIdx.x] + carry_s;
        if (i < N) row_ptr[i + 1] = inc;
        __syncthreads();
        if (threadIdx.x == 255) carry_s = inc;
        __syncthreads();
    }
}

__global__ __launch_bounds__(256) void fill_kernel(
    const int* __restrict__ dst, const int* __restrict__ row_ptr,
    int* __restrict__ fillc, int* __restrict__ edge_idx, int E)
{
    int i = blockIdx.x * 256 + threadIdx.x;
    if (i < E) {
        int d = dst[i];
        int pos = atomicAdd(&fillc[d], 1);
        edge_idx[row_ptr[d] + pos] = i;
    }
}

// ---------------------------------------------------------------- gather ----
__global__ __launch_bounds__(256) void gather_aggr(
    const float* __restrict__ x, const float* __restrict__ e,
    const int* __restrict__ src, const int* __restrict__ row_ptr,
    const int* __restrict__ edge_idx, float* __restrict__ aggr, int N)
{
    int node = blockIdx.x * 4 + (threadIdx.x >> 6);
    if (node >= N) return;
    int lane = threadIdx.x & 63;
    int beg = row_ptr[node], end = row_ptr[node + 1];
    float4 acc = make_float4(0.f, 0.f, 0.f, 0.f);
    for (int j = beg; j < end; ++j) {
        int ed = edge_idx[j];
        int s = src[ed];
        float4 ev = ((const float4*)(e + (size_t)ed * D))[lane];
        float4 xv = ((const float4*)(x + (size_t)s * D))[lane];
        acc.x += fmaxf(ev.x + xv.x, 0.f);
        acc.y += fmaxf(ev.y + xv.y, 0.f);
        acc.z += fmaxf(ev.z + xv.z, 0.f);
        acc.w += fmaxf(ev.w + xv.w, 0.f);
    }
    ((float4*)(aggr + (size_t)node * D))[lane] = acc;
}

// ------------------------------------------- W -> K-chunk-major bf16 hi/lo --
// WT[layer][kc][col][kw]: kc = k/32, kw = k%32. Frag read for (col,kc,l4) is
// 16B at ((kc*256+col)*32 + l4*8); a fragment's 16 cols span 1KB contiguous.
__global__ __launch_bounds__(256) void wconv_kernel(
    const float* __restrict__ W, ushort* __restrict__ WTh,
    ushort* __restrict__ WTl)
{
    int bk = blockIdx.x;            // layer*D + k
    int col = threadIdx.x;
    int layer = bk >> 8, k = bk & 255;
    float v = W[(size_t)bk * D + col];
    ushort h = bf16h(v);
    ushort lo = bf16h(v - bf16f(h));
    size_t o = (((size_t)layer * 8 + (k >> 5)) * 256 + col) * 32 + (k & 31);
    WTh[o] = h;
    WTl[o] = lo;
}

// ----------------------------------------------------- MFMA edge GEMM -------
// block = 64 rows x 256 cols (in-place safe: sole reader+writer of its rows;
// K-loop reads precede the epilogue stores). 4 waves, wave = 64 rows x 64
// cols via 4x4 16x16x32 fragments, hi/lo 3-MFMA split.
// Pipeline per K-step (ONE barrier): issue A(k+1) -> ds_read frags(k) ->
// issue W(k+1) -> 48 MFMA -> cvt+ds_write buf^1 -> barrier. No load crosses
// a barrier; A latency hides under ds_read+MFMA. LDS rows 80B-padded: frag
// reads and staging writes both cover all 32 banks 2-way (free).
__global__ __launch_bounds__(256) void gemm_edge_mfma(
    const float* __restrict__ A, const ushort* __restrict__ WTh,
    const ushort* __restrict__ WTl, const float* __restrict__ bias,
    float* __restrict__ out, int rows)
{
    __shared__ ushort Ah[2][64][40];
    __shared__ ushort Al[2][64][40];
    __shared__ float Tr[4][32][68];   // epilogue transpose

    const int tid  = threadIdx.x;
    const int lane = tid & 63;
    const int wave = tid >> 6;
    const int m0   = blockIdx.x * 64;
    const int l15  = lane & 15;
    const int l4   = lane >> 4;
    const int wcol = wave * 64;

    // staging map: thread -> (row, 8-float sector)
    const int srow = tid >> 2;
    const int ssec = tid & 3;
    const int sgr  = m0 + srow;
    const bool svalid = (sgr < rows);
    const float* aptr = A + (size_t)sgr * D + ssec * 8;

    f32x4 acc[4][4];
#pragma unroll
    for (int m = 0; m < 4; ++m)
#pragma unroll
        for (int n = 0; n < 4; ++n) acc[m][n] = (f32x4){0.f, 0.f, 0.f, 0.f};

    float4 pv0 = make_float4(0.f, 0.f, 0.f, 0.f);
    float4 pv1 = make_float4(0.f, 0.f, 0.f, 0.f);
    bf16x8 bh[4], bl[4], bhn[4], bln[4];

    // ---- prologue: A(kc=0) -> LDS buf0; W(kc=0) -> regs ----
    if (svalid) {
        pv0 = *(const float4*)aptr;
        pv1 = *(const float4*)(aptr + 4);
    }
#pragma unroll
    for (int n = 0; n < 4; ++n) {
        size_t o = ((size_t)(wcol + n * 16 + l15)) * 32 + l4 * 8;
        bh[n] = *(const bf16x8*)(WTh + o);
        bl[n] = *(const bf16x8*)(WTl + o);
    }
    cvt_write8(pv0, pv1, &Ah[0][srow][ssec * 8], &Al[0][srow][ssec * 8]);
    __syncthreads();

    // ---- K loop: 8 chunks of 32 ----
#pragma unroll
    for (int kc = 0; kc < 8; ++kc) {
        const int cur = kc & 1;
        // issue A loads for kc+1 (consumed after the MFMAs)
        if (kc < 7 && svalid) {
            const float* p = aptr + (kc + 1) * 32;
            pv0 = *(const float4*)p;
            pv1 = *(const float4*)(p + 4);
        }
        // own fragments from LDS
        bf16x8 ah[4], al[4];
#pragma unroll
        for (int m = 0; m < 4; ++m) {
            ah[m] = *(const bf16x8*)&Ah[cur][m * 16 + l15][l4 * 8];
            al[m] = *(const bf16x8*)&Al[cur][m * 16 + l15][l4 * 8];
        }
        // issue W loads for kc+1
        if (kc < 7) {
#pragma unroll
            for (int n = 0; n < 4; ++n) {
                size_t o = ((size_t)(kc + 1) * 256 + wcol + n * 16 + l15) * 32
                         + l4 * 8;
                bhn[n] = *(const bf16x8*)(WTh + o);
                bln[n] = *(const bf16x8*)(WTl + o);
            }
        }
#pragma unroll
        for (int m = 0; m < 4; ++m)
#pragma unroll
            for (int n = 0; n < 4; ++n) {
                acc[m][n] = __builtin_amdgcn_mfma_f32_16x16x32_bf16(
                    ah[m], bh[n], acc[m][n], 0, 0, 0);
                acc[m][n] = __builtin_amdgcn_mfma_f32_16x16x32_bf16(
                    ah[m], bl[n], acc[m][n], 0, 0, 0);
                acc[m][n] = __builtin_amdgcn_mfma_f32_16x16x32_bf16(
                    al[m], bh[n], acc[m][n], 0, 0, 0);
            }
        if (kc < 7) {
            cvt_write8(pv0, pv1, &Ah[cur ^ 1][srow][ssec * 8],
                       &Al[cur ^ 1][srow][ssec * 8]);
#pragma unroll
            for (int n = 0; n < 4; ++n) { bh[n] = bhn[n]; bl[n] = bln[n]; }
        }
        __syncthreads();
    }

    // ---- epilogue: bias+relu, LDS transpose, 256B-contiguous stores ----
#pragma unroll
    for (int h = 0; h < 2; ++h) {
        __syncthreads();
#pragma unroll
        for (int mm = 0; mm < 2; ++mm) {
            int m = h * 2 + mm;
#pragma unroll
            for (int n = 0; n < 4; ++n) {
                float bv = bias[wcol + n * 16 + l15];
#pragma unroll
                for (int r = 0; r < 4; ++r)
                    Tr[wave][mm * 16 + l4 * 4 + r][n * 16 + l15] =
                        fmaxf(acc[m][n][r] + bv, 0.f);
            }
        }
        __syncthreads();
#pragma unroll
        for (int p = 0; p < 8; ++p) {
            int row  = p * 4 + l4;
            int grow = m0 + h * 32 + row;
            if (grow < rows) {
                float4 v = *(const float4*)&Tr[wave][row][l15 * 4];
                *(float4*)(out + (size_t)grow * D + wcol + l15 * 4) = v;
            }
        }
    }
}

// ------------------------------------------------------------------- GEMM ----
// fp32 row-full GEMM for node convs (N=10k only). 64 rows x 256 cols/block,
// thread = 4 rows x 16 cols (cols strided jc*64+tx*4: conflict-free).
template<bool HAS_AGGR, bool ADD_INIT>
__global__ __launch_bounds__(256) void gemm_rowfull(
    const float* A, const float* __restrict__ aggr,
    const float* __restrict__ W, const float* __restrict__ bias,
    const float* __restrict__ init, float* out, int rows)
{
    __shared__ float As[16][68];
    __shared__ float Bs[16][260];

    const int tid = threadIdx.x;
    const int m0 = blockIdx.x * 64;
    const int tx = tid & 15;
    const int ty = tid >> 4;

    const int arow = tid >> 2;
    const int ak4  = (tid & 3) << 2;
    const int bk   = tid >> 4;
    const int bn4  = (tid & 15) << 2;

    float acc[4][16];
#pragma unroll
    for (int i = 0; i < 4; ++i)
#pragma unroll
        for (int j = 0; j < 16; ++j) acc[i][j] = 0.f;

    for (int k0 = 0; k0 < D; k0 += 16) {
        float4 av = make_float4(0.f, 0.f, 0.f, 0.f);
        int gr = m0 + arow;
        if (gr < rows) {
            av = *(const float4*)(A + (size_t)gr * D + k0 + ak4);
            if (HAS_AGGR) {
                float4 g = *(const float4*)(aggr + (size_t)gr * D + k0 + ak4);
                av.x += g.x; av.y += g.y; av.z += g.z; av.w += g.w;
            }
        }
        As[ak4 + 0][arow] = av.x;
        As[ak4 + 1][arow] = av.y;
        As[ak4 + 2][arow] = av.z;
        As[ak4 + 3][arow] = av.w;
#pragma unroll
        for (int c = 0; c < 4; ++c)
            *(float4*)&Bs[bk][c * 64 + bn4] =
                *(const float4*)(W + (size_t)(k0 + bk) * D + c * 64 + bn4);
        __syncthreads();
#pragma unroll
        for (int k = 0; k < 16; ++k) {
            float4 a4 = *(const float4*)&As[k][ty << 2];
            float a[4] = {a4.x, a4.y, a4.z, a4.w};
#pragma unroll
            for (int jc = 0; jc < 4; ++jc) {
                float4 b4 = *(const float4*)&Bs[k][(jc << 6) + (tx << 2)];
#pragma unroll
                for (int i = 0; i < 4; ++i) {
                    acc[i][jc * 4 + 0] += a[i] * b4.x;
                    acc[i][jc * 4 + 1] += a[i] * b4.y;
                    acc[i][jc * 4 + 2] += a[i] * b4.z;
                    acc[i][jc * 4 + 3] += a[i] * b4.w;
                }
            }
        }
        __syncthreads();
    }

#pragma unroll
    for (int jc = 0; jc < 4; ++jc) {
        int col = (jc << 6) + (tx << 2);
        float4 bias4 = *(const float4*)(bias + col);
#pragma unroll
        for (int i = 0; i < 4; ++i) {
            int gr = m0 + (ty << 2) + i;
            if (gr < rows) {
                float4 o;
                o.x = fmaxf(acc[i][jc * 4 + 0] + bias4.x, 0.f);
                o.y = fmaxf(acc[i][jc * 4 + 1] + bias4.y, 0.f);
                o.z = fmaxf(acc[i][jc * 4 + 2] + bias4.z, 0.f);
                o.w = fmaxf(acc[i][jc * 4 + 3] + bias4.w, 0.f);
                if (ADD_INIT) {
                    float4 iv = *(const float4*)(init + (size_t)gr * D + col);
                    o.x += iv.x; o.y += iv.y; o.z += iv.z; o.w += iv.w;
                }
                *(float4*)(out + (size_t)gr * D + col) = o;
            }
        }
    }
}

// --------------------------------------------------------------------- BN ----
__global__ __launch_bounds__(256) void bn_stats_kernel(
    const float* __restrict__ x, float* __restrict__ stats, int N)
{
    int col = threadIdx.x;
    float s = 0.f, s2 = 0.f;
    for (int r = blockIdx.x; r < N; r += gridDim.x) {
        float v = x[(size_t)r * D + col];
        s += v; s2 += v * v;
    }
    atomicAdd(&stats[col], s);
    atomicAdd(&stats[D + col], s2);
}

__global__ __launch_bounds__(256) void bn_apply_kernel(
    float* __restrict__ x, const float* __restrict__ stats,
    const float* __restrict__ gamma, const float* __restrict__ beta, int N)
{
    int col = threadIdx.x;
    float inv_n = 1.f / (float)N;
    float mean = stats[col] * inv_n;
    float var  = stats[D + col] * inv_n - mean * mean;
    float scale = gamma[col] * rsqrtf(var + BN_EPS);
    float shift = beta[col] - mean * scale;
    for (int r = blockIdx.x; r < N; r += gridDim.x) {
        size_t idx = (size_t)r * D + col;
        x[idx] = x[idx] * scale + shift;
    }
}

// ----------------------------------------------------------------- launch ----
extern "C" void kernel_launch(void* const* d_in, const int* in_sizes, int n_in,
                              void* d_out, int out_size, void* d_ws, size_t ws_size,
                              hipStream_t stream)
{
    const float* node_feat = (const float*)d_in[0];
    float*       e         = (float*)d_in[1];   // in place (harness restores)
    const int*   src       = (const int*)d_in[2];
    const int*   dst       = (const int*)d_in[3];
    const float* W_conv    = (const float*)d_in[4];
    const float* b_conv    = (const float*)d_in[5];
    const float* W_edge    = (const float*)d_in[6];
    const float* b_edge    = (const float*)d_in[7];
    const float* gamma     = (const float*)d_in[8];
    const float* beta      = (const float*)d_in[9];
    float*       out       = (float*)d_out;

    const int N = in_sizes[0] / D;
    const int E = in_sizes[2];
    const int L = in_sizes[5] / D;

    float* x        = (float*)d_ws;                  // N*D f32
    float* aggr     = x + (size_t)N * D;             // N*D f32
    float* stats    = aggr + (size_t)N * D;          // 2*D f32
    int*   cnt      = (int*)(stats + 2 * D);         // N
    int*   row_ptr  = cnt + N;                       // N+1
    int*   fillc    = row_ptr + N + 1;               // N
    int*   edge_idx = fillc + N;                     // E
    ushort* WTh     = (ushort*)(edge_idx + E);       // L*D*D bf16 hi
    ushort* WTl     = WTh + (size_t)L * D * D;       // L*D*D bf16 lo

    int nodeBlocks    = (N + 63) / 64;
    int edgeBlocks    = (E + 63) / 64;
    int gatherBlocks  = (N + 3) / 4;
    int eThreadBlocks = (E + 255) / 256;

    // ---- one-time: CSR over dst + W_edge -> K-chunk-major bf16 hi/lo ----
    hipMemsetAsync(cnt, 0, (size_t)N * sizeof(int), stream);
    hipMemsetAsync(fillc, 0, (size_t)N * sizeof(int), stream);
    hist_kernel<<<eThreadBlocks, 256, 0, stream>>>(dst, cnt, E);
    scan_kernel<<<1, 256, 0, stream>>>(cnt, row_ptr, N);
    fill_kernel<<<eThreadBlocks, 256, 0, stream>>>(dst, row_ptr, fillc, edge_idx, E);
    wconv_kernel<<<L * D, 256, 0, stream>>>(W_edge, WTh, WTl);

    const float* xin = node_feat;
    for (int i = 0; i < L; ++i) {
        gather_aggr<<<gatherBlocks, 256, 0, stream>>>(
            xin, e, src, row_ptr, edge_idx, aggr, N);
        gemm_rowfull<true, false><<<nodeBlocks, 256, 0, stream>>>(
            xin, aggr, W_conv + (size_t)i * D * D, b_conv + (size_t)i * D,
            nullptr, x, N);
        hipMemsetAsync(stats, 0, 2 * D * sizeof(float), stream);
        bn_stats_kernel<<<512, 256, 0, stream>>>(x, stats, N);
        bn_apply_kernel<<<1024, 256, 0, stream>>>(
            x, stats, gamma + (size_t)i * D, beta + (size_t)i * D, N);
        gemm_edge_mfma<<<edgeBlocks, 256, 0, stream>>>(
            e, WTh + (size_t)i * D * D, WTl + (size_t)i * D * D,
            b_edge + (size_t)i * D, e, E);
        xin = x;
    }

    // final conv: layer L-1 weights on current (x, e), then + node_feat
    gather_aggr<<<gatherBlocks, 256, 0, stream>>>(
        x, e, src, row_ptr, edge_idx, aggr, N);
    gemm_rowfull<true, true><<<nodeBlocks, 256, 0, stream>>>(
        x, aggr, W_conv + (size_t)(L - 1) * D * D, b_conv + (size_t)(L - 1) * D,
        node_feat, out, N);
}